// Round 8
// baseline (168.897 us; speedup 1.0000x reference)
//
#include <hip/hip_runtime.h>

#define NN 50000
#define NE 800000
#define KH 4
#define FIN 6
#define FH 128
#define FO 6
#define ADIM 3
#define NN6 (NN * 6)
#define NBKT 196        // ceil(NN / 256) buckets of 256 node ids
#define EPB 2048        // edges per partition block
#define NPB 391         // ceil(NE / EPB)
#define CAP 5120        // LDS staging capacity per bucket
#define ROWMASK 0xFFFFFu
#define GFUSE 2048      // grid for fused dense kernel
#define LPN 16          // lanes per node in hop kernels (avg degree 16 -> 1 iter/lane)

typedef unsigned int u32;

struct __align__(8) Edge { u32 r; float w; };

// ---------------- K1: bucket histogram (col >> 8) ----------------
__global__ void bucket_hist(const int* __restrict__ col, u32* __restrict__ ghist) {
    __shared__ u32 h[NBKT];
    for (int t = threadIdx.x; t < NBKT; t += 256) h[t] = 0;
    __syncthreads();
    int base = blockIdx.x * EPB;
#pragma unroll
    for (int i = 0; i < EPB / 256; ++i) {
        int e = base + i * 256 + threadIdx.x;
        if (e < NE) atomicAdd(&h[((u32)col[e]) >> 8], 1u);
    }
    __syncthreads();
    for (int t = threadIdx.x; t < NBKT; t += 256)
        if (h[t]) atomicAdd(&ghist[t], h[t]);
}

// ---------------- K2: scan bucket counts -> bases/cursors ----------------
__global__ void bucket_scan(const u32* __restrict__ ghist, u32* __restrict__ bbase,
                            u32* __restrict__ bcur, int* __restrict__ offs) {
    __shared__ u32 sh[256];
    int t = threadIdx.x;
    u32 v = (t < NBKT) ? ghist[t] : 0;
    sh[t] = v;
    __syncthreads();
    for (int off = 1; off < 256; off <<= 1) {
        u32 u = (t >= off) ? sh[t - off] : 0;
        __syncthreads();
        sh[t] += u;
        __syncthreads();
    }
    if (t < NBKT) { bbase[t] = sh[t] - v; bcur[t] = sh[t] - v; }
    if (t == NBKT - 1) bbase[NBKT] = sh[t];
    if (t == 0) offs[NN] = NE;
}

// ---------------- K3: partition edges into bucket-grouped etmp (LDS-staged) ----------------
__global__ __launch_bounds__(256) void partition_kernel(
        const int* __restrict__ row, const int* __restrict__ col,
        const float* __restrict__ w, u32* __restrict__ bcur,
        Edge* __restrict__ etmp) {
    __shared__ u32 hcnt[NBKT];
    __shared__ u32 hloc[NBKT];
    __shared__ u32 hglb[NBKT];
    __shared__ u32 smeta[EPB];
    __shared__ float swt[EPB];
    __shared__ u32 sgid[EPB];
    __shared__ u32 sc[256];
    for (int t = threadIdx.x; t < NBKT; t += 256) hcnt[t] = 0;
    __syncthreads();
    int base = blockIdx.x * EPB;
    u32 m_[8]; float w_[8]; u32 b_[8]; u32 rk_[8]; int v_[8];
#pragma unroll
    for (int i = 0; i < 8; ++i) {
        int e = base + i * 256 + threadIdx.x;
        v_[i] = e < NE;
        if (v_[i]) {
            u32 c = (u32)col[e];
            u32 r = (u32)row[e];
            b_[i] = c >> 8;
            m_[i] = ((c & 255u) << 20) | r;
            w_[i] = w[e];
            rk_[i] = atomicAdd(&hcnt[b_[i]], 1u);
        }
    }
    __syncthreads();
    {   // exclusive scan of hcnt -> hloc
        int t = threadIdx.x;
        u32 v = (t < NBKT) ? hcnt[t] : 0;
        sc[t] = v;
        __syncthreads();
        for (int off = 1; off < 256; off <<= 1) {
            u32 u = (t >= off) ? sc[t - off] : 0;
            __syncthreads();
            sc[t] += u;
            __syncthreads();
        }
        if (t < NBKT) hloc[t] = sc[t] - v;
    }
    __syncthreads();
    for (int t = threadIdx.x; t < NBKT; t += 256)
        if (hcnt[t]) hglb[t] = atomicAdd(&bcur[t], hcnt[t]);
    __syncthreads();
#pragma unroll
    for (int i = 0; i < 8; ++i) if (v_[i]) {
        u32 slot = hloc[b_[i]] + rk_[i];
        smeta[slot] = m_[i];
        swt[slot] = w_[i];
        sgid[slot] = hglb[b_[i]] + rk_[i];
    }
    __syncthreads();
    int tot = NE - base; if (tot > EPB) tot = EPB;
    for (int s = threadIdx.x; s < tot; s += 256) {
        Edge ed; ed.r = smeta[s]; ed.w = swt[s];
        etmp[sgid[s]] = ed;
    }
}

// ---------------- K4: per-bucket CSR build + deg/dinv + offs (no global atomics) ----------------
__global__ __launch_bounds__(256) void bucket_csr(
        const u32* __restrict__ bbase, const Edge* __restrict__ etmp,
        Edge* __restrict__ edges, int* __restrict__ offs,
        float* __restrict__ dinv) {
    int b = blockIdx.x;
    int t = threadIdx.x;
    u32 s = bbase[b], e = bbase[b + 1];
    int cnt = (int)(e - s);
    int node0 = b << 8;
    int nloc = NN - node0; if (nloc > 256) nloc = 256;
    __shared__ u32 ncnt[256];
    __shared__ float nsum[256];
    __shared__ u32 ncur[256];
    __shared__ u32 sc[256];
    __shared__ Edge stage[CAP];   // 40 KB
    ncnt[t] = 0; nsum[t] = 0.f;
    __syncthreads();
    for (int i = t; i < cnt; i += 256) {
        Edge ed = etmp[s + i];
        u32 cl = ed.r >> 20;
        atomicAdd(&ncnt[cl], 1u);
        atomicAdd(&nsum[cl], ed.w);
    }
    __syncthreads();
    u32 v = ncnt[t];
    sc[t] = v;
    __syncthreads();
    for (int off = 1; off < 256; off <<= 1) {
        u32 u = (t >= off) ? sc[t - off] : 0;
        __syncthreads();
        sc[t] += u;
        __syncthreads();
    }
    u32 excl = sc[t] - v;
    ncur[t] = excl;
    if (t < nloc) {
        offs[node0 + t] = (int)(s + excl);
        float d = nsum[t];
        dinv[node0 + t] = d > 0.f ? rsqrtf(d) : 0.f;
    }
    __syncthreads();
    for (int i = t; i < cnt; i += 256) {
        Edge ed = etmp[s + i];
        u32 cl = ed.r >> 20;
        u32 slot = atomicAdd(&ncur[cl], 1u);
        Edge ce; ce.r = ed.r & ROWMASK; ce.w = ed.w;
        if (slot < CAP) stage[slot] = ce;
        else edges[s + slot] = ce;
    }
    __syncthreads();
    int lim = cnt < CAP ? cnt : CAP;
    for (int i = t; i < lim; i += 256) edges[s + i] = stage[i];
}

// ---------------- shared 16-lane reduce + write helper ----------------
__device__ __forceinline__ void hop_reduce_write(
        int n, int j, float a0, float a1, float a2, float a3, float a4, float a5,
        const float* yadd, int yst, float* xnext) {
#pragma unroll
    for (int d = 1; d < LPN; d <<= 1) {
        a0 += __shfl_xor(a0, d); a1 += __shfl_xor(a1, d); a2 += __shfl_xor(a2, d);
        a3 += __shfl_xor(a3, d); a4 += __shfl_xor(a4, d); a5 += __shfl_xor(a5, d);
    }
    if (j < 6) {
        float v = j == 0 ? a0 : j == 1 ? a1 : j == 2 ? a2 : j == 3 ? a3 : j == 4 ? a4 : a5;
        if (yadd) v += yadd[(size_t)n * yst + j];
        xnext[n * 6 + j] = v;
    }
}

// ---------------- hop variant 1: normalize-in-place + first hop (xprev = x, stride 6) ----------------
__global__ void hop16_norm(const int* __restrict__ offs, Edge* __restrict__ edges,
                           const float* __restrict__ dinv, const float* __restrict__ xprev,
                           float* __restrict__ xnext) {
    int t = blockIdx.x * blockDim.x + threadIdx.x;
    int n = t >> 4, j = t & 15;
    if (n >= NN) return;
    int s = offs[n], e = offs[n + 1];
    float dn = dinv[n];
    float a0 = 0.f, a1 = 0.f, a2 = 0.f, a3 = 0.f, a4 = 0.f, a5 = 0.f;
    for (int i = s + j; i < e; i += LPN) {
        Edge ed = edges[i];
        float wn = ed.w * dn * dinv[ed.r];
        ed.w = wn;
        edges[i] = ed;                       // persist normalized weight for later hops
        const float* xr = xprev + (size_t)ed.r * 6;
        a0 += wn * xr[0]; a1 += wn * xr[1]; a2 += wn * xr[2];
        a3 += wn * xr[3]; a4 += wn * xr[4]; a5 += wn * xr[5];
    }
    hop_reduce_write(n, j, a0, a1, a2, a3, a4, a5, nullptr, 0, xnext);
}

// ---------------- hop: 16 lanes/node; xnext = yadd + A * xprev(stride xst, offset xof) ----------------
__global__ void hop16(const int* __restrict__ offs, const Edge* __restrict__ edges,
                      const float* __restrict__ xprev, int xst, int xof,
                      const float* __restrict__ yadd,
                      float* __restrict__ xnext) {
    int t = blockIdx.x * blockDim.x + threadIdx.x;
    int n = t >> 4, j = t & 15;
    if (n >= NN) return;
    int s = offs[n], e = offs[n + 1];
    float a0 = 0.f, a1 = 0.f, a2 = 0.f, a3 = 0.f, a4 = 0.f, a5 = 0.f;
    for (int i = s + j; i < e; i += LPN) {
        Edge ed = edges[i];
        const float* xr = xprev + (size_t)ed.r * xst + xof;
        a0 += ed.w * xr[0]; a1 += ed.w * xr[1]; a2 += ed.w * xr[2];
        a3 += ed.w * xr[3]; a4 += ed.w * xr[4]; a5 += ed.w * xr[5];
    }
    hop_reduce_write(n, j, a0, a1, a2, a3, a4, a5, yadd, 30, xnext);
}

// ---------------- final hop fused with tanh/exp finalize ----------------
__global__ void hop16_final(const int* __restrict__ offs, const Edge* __restrict__ edges,
                            const float* __restrict__ xprev, const float* __restrict__ y0,
                            float* __restrict__ out) {
    int t = blockIdx.x * blockDim.x + threadIdx.x;
    int n = t >> 4, j = t & 15;
    if (n >= NN) return;
    int s = offs[n], e = offs[n + 1];
    float a0 = 0.f, a1 = 0.f, a2 = 0.f, a3 = 0.f, a4 = 0.f, a5 = 0.f;
    for (int i = s + j; i < e; i += LPN) {
        Edge ed = edges[i];
        const float* xr = xprev + (size_t)ed.r * 6;
        a0 += ed.w * xr[0]; a1 += ed.w * xr[1]; a2 += ed.w * xr[2];
        a3 += ed.w * xr[3]; a4 += ed.w * xr[4]; a5 += ed.w * xr[5];
    }
#pragma unroll
    for (int d = 1; d < LPN; d <<= 1) {
        a0 += __shfl_xor(a0, d); a1 += __shfl_xor(a1, d); a2 += __shfl_xor(a2, d);
        a3 += __shfl_xor(a3, d); a4 += __shfl_xor(a4, d); a5 += __shfl_xor(a5, d);
    }
    if (j < 6) {
        float v = j == 0 ? a0 : j == 1 ? a1 : j == 2 ? a2 : j == 3 ? a3 : j == 4 ? a4 : a5;
        v += y0[(size_t)n * 30 + j];               // ys node-major, k=0 slice
        float tv = tanhf(v);
        if (j < ADIM) out[n * ADIM + j] = tv;
        else          out[NN * ADIM + n * ADIM + (j - ADIM)] = expf(2.f * tv);
    }
}

// ---------------- fused dense: ys[n][k][a] = (relu(sum xs@W1 + b1)) @ W2[k] (+b2 k=0) ----------------
__global__ __launch_bounds__(256) void fused_dense_kernel(
        const float* __restrict__ x, const float* __restrict__ xs,
        const float* __restrict__ W1, const float* __restrict__ b1,
        const float* __restrict__ W2, const float* __restrict__ b2,
        float* __restrict__ ys) {
    __shared__ float sin_[2][32];
    __shared__ float sh[2][128];
    int t = threadIdx.x;
    int f = t & 127, half = t >> 7;
    float w1r[30];
#pragma unroll
    for (int i = 0; i < 30; ++i) w1r[i] = W1[i * FH + f];
    float b1r = b1[f];
    bool bact = t < 240;
    int bn = t / 120;
    int rem = t % 120;
    int ka = rem >> 2;          // 0..29
    int q  = rem & 3;
    int k2 = ka / 6, a2 = ka - k2 * 6;
    float w2r[32];
#pragma unroll
    for (int i = 0; i < 32; ++i)
        w2r[i] = bact ? W2[((size_t)k2 * FH + q * 32 + i) * FO + a2] : 0.f;
    float badd = (bact && k2 == 0 && q == 0) ? b2[a2] : 0.f;

    for (int n0 = blockIdx.x * 2; n0 < NN; n0 += GFUSE * 2) {
        if (t < 60) {
            int nn = t / 30, c = t - nn * 30;
            int n = n0 + nn;
            float v;
            if (c < 6) v = x[n * 6 + c];
            else       v = xs[(size_t)((c - 6) / 6) * NN6 + n * 6 + (c - 6) % 6];
            sin_[nn][c] = v;
        }
        __syncthreads();
        {
            float s = b1r;
#pragma unroll
            for (int i = 0; i < 30; ++i) s += sin_[half][i] * w1r[i];
            sh[half][f] = s > 0.f ? s : 0.f;
        }
        __syncthreads();
        if (bact) {
            float s = badd;
            const float* hr = &sh[bn][q * 32];
#pragma unroll
            for (int i = 0; i < 32; ++i) s += hr[i] * w2r[i];
            s += __shfl_xor(s, 1);
            s += __shfl_xor(s, 2);
            if (q == 0) ys[(size_t)(n0 + bn) * 30 + ka] = s;
        }
    }
}

extern "C" void kernel_launch(void* const* d_in, const int* in_sizes, int n_in,
                              void* d_out, int out_size, void* d_ws, size_t ws_size,
                              hipStream_t stream) {
    const float* x  = (const float*)d_in[0];
    const int*   ei = (const int*)d_in[1];
    const float* ew = (const float*)d_in[2];
    const float* W1 = (const float*)d_in[3];
    const float* b1 = (const float*)d_in[4];
    const float* W2 = (const float*)d_in[5];
    const float* b2 = (const float*)d_in[6];
    float* out = (float*)d_out;

    const int* row = ei;
    const int* col = ei + NE;

    // workspace layout (8B-aligned Edge arrays first)
    Edge*  etmp  = (Edge*)d_ws;                 // NE
    Edge*  edges = etmp + NE;                   // NE
    u32*   ghist = (u32*)(edges + NE);          // NBKT
    u32*   bbase = ghist + NBKT;                // NBKT+1
    u32*   bcur  = bbase + NBKT + 1;            // NBKT
    int*   offs  = (int*)(bcur + NBKT);         // NN+1
    float* dinv  = (float*)(offs + NN + 1);     // NN
    float* xs    = dinv + NN;                   // KH*NN6
    float* ys    = xs + (size_t)KH * NN6;       // NN*30 (node-major [n][5][6])
    float* za    = ys + (size_t)NN * 30;        // NN6
    float* zb    = za + NN6;                    // NN6

    const int B = 256;
    const int gHop = (NN * LPN + B - 1) / B;

    // ---- CSR build ----
    hipMemsetAsync(ghist, 0, NBKT * sizeof(u32), stream);
    bucket_hist<<<NPB, B, 0, stream>>>(col, ghist);
    bucket_scan<<<1, B, 0, stream>>>(ghist, bbase, bcur, offs);
    partition_kernel<<<NPB, B, 0, stream>>>(row, col, ew, bcur, etmp);
    bucket_csr<<<NBKT, B, 0, stream>>>(bbase, etmp, edges, offs, dinv);

    // ---- layer 1: hops on 6-wide input features (hop 1 fuses normalization) ----
    hop16_norm<<<gHop, B, 0, stream>>>(offs, edges, dinv, x, xs);
    for (int k = 2; k <= KH; ++k)
        hop16<<<gHop, B, 0, stream>>>(offs, edges,
                                      xs + (size_t)(k - 2) * NN6, 6, 0, nullptr,
                                      xs + (size_t)(k - 1) * NN6);

    // ---- fused dense1 + relu + proj2 ----
    fused_dense_kernel<<<GFUSE, B, 0, stream>>>(x, xs, W1, b1, W2, b2, ys);

    // ---- layer 2 Horner on 6-wide ----
    hop16<<<gHop, B, 0, stream>>>(offs, edges, ys, 30, 24, ys + 18, za);
    hop16<<<gHop, B, 0, stream>>>(offs, edges, za, 6, 0, ys + 12, zb);
    hop16<<<gHop, B, 0, stream>>>(offs, edges, zb, 6, 0, ys + 6, za);
    hop16_final<<<gHop, B, 0, stream>>>(offs, edges, za, ys, out);
}

// Round 9
// 166.502 us; speedup vs baseline: 1.0144x; 1.0144x over previous
//
#include <hip/hip_runtime.h>

#define NN 50000
#define NE 800000
#define KH 4
#define FIN 6
#define FH 128
#define FO 6
#define ADIM 3
#define NN6 (NN * 6)
#define NN8 (NN * 8)
#define NBKT 196        // ceil(NN / 256) buckets of 256 node ids
#define EPB 2048        // edges per partition block
#define NPB 391         // ceil(NE / EPB)
#define CAP 5120        // LDS staging capacity per bucket (holds padded count too)
#define ROWMASK 0xFFFFFu
#define GFUSE 2048      // grid for fused dense kernel
#define NEPAD (NE + NBKT * 256)   // padded edge capacity

typedef unsigned int u32;

struct __align__(8) Edge { u32 r; float w; };

// ---------------- K1: bucket histogram (col >> 8) ----------------
__global__ void bucket_hist(const int* __restrict__ col, u32* __restrict__ ghist) {
    __shared__ u32 h[NBKT];
    for (int t = threadIdx.x; t < NBKT; t += 256) h[t] = 0;
    __syncthreads();
    int base = blockIdx.x * EPB;
#pragma unroll
    for (int i = 0; i < EPB / 256; ++i) {
        int e = base + i * 256 + threadIdx.x;
        if (e < NE) atomicAdd(&h[((u32)col[e]) >> 8], 1u);
    }
    __syncthreads();
    for (int t = threadIdx.x; t < NBKT; t += 256)
        if (h[t]) atomicAdd(&ghist[t], h[t]);
}

// ---------------- K2: scan bucket counts -> bases/cursors ----------------
__global__ void bucket_scan(const u32* __restrict__ ghist, u32* __restrict__ bbase,
                            u32* __restrict__ bcur) {
    __shared__ u32 sh[256];
    int t = threadIdx.x;
    u32 v = (t < NBKT) ? ghist[t] : 0;
    sh[t] = v;
    __syncthreads();
    for (int off = 1; off < 256; off <<= 1) {
        u32 u = (t >= off) ? sh[t - off] : 0;
        __syncthreads();
        sh[t] += u;
        __syncthreads();
    }
    if (t < NBKT) { bbase[t] = sh[t] - v; bcur[t] = sh[t] - v; }
    if (t == NBKT - 1) bbase[NBKT] = sh[t];
}

// ---------------- K3: partition edges into bucket-grouped etmp (LDS-staged) ----------------
__global__ __launch_bounds__(256) void partition_kernel(
        const int* __restrict__ row, const int* __restrict__ col,
        const float* __restrict__ w, u32* __restrict__ bcur,
        Edge* __restrict__ etmp) {
    __shared__ u32 hcnt[NBKT];
    __shared__ u32 hloc[NBKT];
    __shared__ u32 hglb[NBKT];
    __shared__ u32 smeta[EPB];
    __shared__ float swt[EPB];
    __shared__ u32 sgid[EPB];
    __shared__ u32 sc[256];
    for (int t = threadIdx.x; t < NBKT; t += 256) hcnt[t] = 0;
    __syncthreads();
    int base = blockIdx.x * EPB;
    u32 m_[8]; float w_[8]; u32 b_[8]; u32 rk_[8]; int v_[8];
#pragma unroll
    for (int i = 0; i < 8; ++i) {
        int e = base + i * 256 + threadIdx.x;
        v_[i] = e < NE;
        if (v_[i]) {
            u32 c = (u32)col[e];
            u32 r = (u32)row[e];
            b_[i] = c >> 8;
            m_[i] = ((c & 255u) << 20) | r;
            w_[i] = w[e];
            rk_[i] = atomicAdd(&hcnt[b_[i]], 1u);
        }
    }
    __syncthreads();
    {   // exclusive scan of hcnt -> hloc
        int t = threadIdx.x;
        u32 v = (t < NBKT) ? hcnt[t] : 0;
        sc[t] = v;
        __syncthreads();
        for (int off = 1; off < 256; off <<= 1) {
            u32 u = (t >= off) ? sc[t - off] : 0;
            __syncthreads();
            sc[t] += u;
            __syncthreads();
        }
        if (t < NBKT) hloc[t] = sc[t] - v;
    }
    __syncthreads();
    for (int t = threadIdx.x; t < NBKT; t += 256)
        if (hcnt[t]) hglb[t] = atomicAdd(&bcur[t], hcnt[t]);
    __syncthreads();
#pragma unroll
    for (int i = 0; i < 8; ++i) if (v_[i]) {
        u32 slot = hloc[b_[i]] + rk_[i];
        smeta[slot] = m_[i];
        swt[slot] = w_[i];
        sgid[slot] = hglb[b_[i]] + rk_[i];
    }
    __syncthreads();
    int tot = NE - base; if (tot > EPB) tot = EPB;
    for (int s = threadIdx.x; s < tot; s += 256) {
        Edge ed; ed.r = smeta[s]; ed.w = swt[s];
        etmp[sgid[s]] = ed;
    }
}

// ---------------- K4: per-bucket CSR build (even-padded segments) ----------------
__global__ __launch_bounds__(256) void bucket_csr(
        const u32* __restrict__ bbase, const Edge* __restrict__ etmp,
        Edge* __restrict__ edges, int* __restrict__ offs, int* __restrict__ eoff,
        float* __restrict__ dinv) {
    int b = blockIdx.x;
    int t = threadIdx.x;
    u32 s = bbase[b], e = bbase[b + 1];
    int cnt = (int)(e - s);
    u32 rb = s + (u32)b * 256u;          // padded region base (each bucket gets +256 slack)
    int node0 = b << 8;
    int nloc = NN - node0; if (nloc > 256) nloc = 256;
    __shared__ u32 ncnt[256];
    __shared__ float nsum[256];
    __shared__ u32 ncur[256];
    __shared__ u32 sc[256];
    __shared__ Edge stage[CAP];   // 40 KB
    ncnt[t] = 0; nsum[t] = 0.f;
    __syncthreads();
    for (int i = t; i < cnt; i += 256) {
        Edge ed = etmp[s + i];
        u32 cl = ed.r >> 20;
        atomicAdd(&ncnt[cl], 1u);
        atomicAdd(&nsum[cl], ed.w);
    }
    __syncthreads();
    u32 v = ncnt[t];
    u32 pv = (v + 1u) & ~1u;             // pad each node's segment to even length
    sc[t] = pv;
    __syncthreads();
    for (int off = 1; off < 256; off <<= 1) {
        u32 u = (t >= off) ? sc[t - off] : 0;
        __syncthreads();
        sc[t] += u;
        __syncthreads();
    }
    u32 excl = sc[t] - pv;
    u32 ptot = sc[255];
    ncur[t] = excl;
    if (t < nloc) {
        offs[node0 + t] = (int)(rb + excl);
        eoff[node0 + t] = (int)(rb + excl + pv);
        float d = nsum[t];
        dinv[node0 + t] = d > 0.f ? rsqrtf(d) : 0.f;
    }
    __syncthreads();
    for (int i = t; i < cnt; i += 256) {
        Edge ed = etmp[s + i];
        u32 cl = ed.r >> 20;
        u32 slot = atomicAdd(&ncur[cl], 1u);
        Edge ce; ce.r = ed.r & ROWMASK; ce.w = ed.w;
        if (slot < CAP) stage[slot] = ce;
        else edges[rb + slot] = ce;
    }
    if (t < nloc && (v & 1u)) {          // zero-edge pad for odd-degree nodes
        u32 slot = excl + v;
        Edge ce; ce.r = 0u; ce.w = 0.f;
        if (slot < CAP) stage[slot] = ce;
        else edges[rb + slot] = ce;
    }
    __syncthreads();
    int lim = (int)(ptot < CAP ? ptot : CAP);
    for (int i = t; i < lim; i += 256) edges[rb + i] = stage[i];
}

// ---------------- pad x rows to stride 8 (16B-aligned gathers) ----------------
__global__ void pad_x(const float* __restrict__ x, float* __restrict__ xpad) {
    int t = blockIdx.x * blockDim.x + threadIdx.x;
    if (t >= NN8) return;
    int n = t >> 3, c = t & 7;
    xpad[t] = (c < 6) ? x[n * 6 + c] : 0.f;
}

// ---------------- gather helper: 24B aligned row = float4 + float2 (2 VMEM) ----------------
__device__ __forceinline__ void gather6(const float* __restrict__ base, u32 r,
                                        int xst, int xof, float w,
                                        float& a0, float& a1, float& a2,
                                        float& a3, float& a4, float& a5) {
    const float* xr = base + (size_t)r * xst + xof;
    float4 u = *(const float4*)xr;
    float2 v = *(const float2*)(xr + 4);
    a0 += w * u.x; a1 += w * u.y; a2 += w * u.z;
    a3 += w * u.w; a4 += w * v.x; a5 += w * v.y;
}

// ---------------- hop: 8 lanes/node, edge-pair loads; xnext(stride8) = yadd + A*xprev ----------------
__global__ void hop8(const int* __restrict__ offs, const int* __restrict__ eoff,
                     const Edge* __restrict__ edges,
                     const float* __restrict__ xprev, int xst, int xof,
                     const float* __restrict__ yadd,
                     float* __restrict__ xnext) {
    int t = blockIdx.x * blockDim.x + threadIdx.x;
    int n = t >> 3, j = t & 7;
    if (n >= NN) return;
    int s = offs[n], e = eoff[n];
    float a0 = 0.f, a1 = 0.f, a2 = 0.f, a3 = 0.f, a4 = 0.f, a5 = 0.f;
    for (int i = s + 2 * j; i < e; i += 16) {
        int4 ep = *(const int4*)&edges[i];   // 2 edges, 16B aligned (segments even-based)
        gather6(xprev, (u32)ep.x, xst, xof, __int_as_float(ep.y), a0, a1, a2, a3, a4, a5);
        gather6(xprev, (u32)ep.z, xst, xof, __int_as_float(ep.w), a0, a1, a2, a3, a4, a5);
    }
#pragma unroll
    for (int d = 1; d < 8; d <<= 1) {
        a0 += __shfl_xor(a0, d); a1 += __shfl_xor(a1, d); a2 += __shfl_xor(a2, d);
        a3 += __shfl_xor(a3, d); a4 += __shfl_xor(a4, d); a5 += __shfl_xor(a5, d);
    }
    if (j < 6) {
        float v = j == 0 ? a0 : j == 1 ? a1 : j == 2 ? a2 : j == 3 ? a3 : j == 4 ? a4 : a5;
        if (yadd) v += yadd[(size_t)n * 32 + j];   // ys node-major [n][32], caller pre-offsets k*6
        xnext[n * 8 + j] = v;
    }
}

// ---------------- hop variant: normalize-in-place + first hop (gathers xpad) ----------------
__global__ void hop8_norm(const int* __restrict__ offs, const int* __restrict__ eoff,
                          Edge* __restrict__ edges,
                          const float* __restrict__ dinv, const float* __restrict__ xpad,
                          float* __restrict__ xnext) {
    int t = blockIdx.x * blockDim.x + threadIdx.x;
    int n = t >> 3, j = t & 7;
    if (n >= NN) return;
    int s = offs[n], e = eoff[n];
    float dn = dinv[n];
    float a0 = 0.f, a1 = 0.f, a2 = 0.f, a3 = 0.f, a4 = 0.f, a5 = 0.f;
    for (int i = s + 2 * j; i < e; i += 16) {
        int4 ep = *(const int4*)&edges[i];
        u32 r0 = (u32)ep.x, r1 = (u32)ep.z;
        float wn0 = __int_as_float(ep.y) * dn * dinv[r0];
        float wn1 = __int_as_float(ep.w) * dn * dinv[r1];
        ep.y = __float_as_int(wn0); ep.w = __float_as_int(wn1);
        *(int4*)&edges[i] = ep;              // persist normalized weights
        gather6(xpad, r0, 8, 0, wn0, a0, a1, a2, a3, a4, a5);
        gather6(xpad, r1, 8, 0, wn1, a0, a1, a2, a3, a4, a5);
    }
#pragma unroll
    for (int d = 1; d < 8; d <<= 1) {
        a0 += __shfl_xor(a0, d); a1 += __shfl_xor(a1, d); a2 += __shfl_xor(a2, d);
        a3 += __shfl_xor(a3, d); a4 += __shfl_xor(a4, d); a5 += __shfl_xor(a5, d);
    }
    if (j < 6) {
        float v = j == 0 ? a0 : j == 1 ? a1 : j == 2 ? a2 : j == 3 ? a3 : j == 4 ? a4 : a5;
        xnext[n * 8 + j] = v;
    }
}

// ---------------- final hop fused with tanh/exp finalize ----------------
__global__ void hop8_final(const int* __restrict__ offs, const int* __restrict__ eoff,
                           const Edge* __restrict__ edges,
                           const float* __restrict__ xprev, const float* __restrict__ y0,
                           float* __restrict__ out) {
    int t = blockIdx.x * blockDim.x + threadIdx.x;
    int n = t >> 3, j = t & 7;
    if (n >= NN) return;
    int s = offs[n], e = eoff[n];
    float a0 = 0.f, a1 = 0.f, a2 = 0.f, a3 = 0.f, a4 = 0.f, a5 = 0.f;
    for (int i = s + 2 * j; i < e; i += 16) {
        int4 ep = *(const int4*)&edges[i];
        gather6(xprev, (u32)ep.x, 8, 0, __int_as_float(ep.y), a0, a1, a2, a3, a4, a5);
        gather6(xprev, (u32)ep.z, 8, 0, __int_as_float(ep.w), a0, a1, a2, a3, a4, a5);
    }
#pragma unroll
    for (int d = 1; d < 8; d <<= 1) {
        a0 += __shfl_xor(a0, d); a1 += __shfl_xor(a1, d); a2 += __shfl_xor(a2, d);
        a3 += __shfl_xor(a3, d); a4 += __shfl_xor(a4, d); a5 += __shfl_xor(a5, d);
    }
    if (j < 6) {
        float v = j == 0 ? a0 : j == 1 ? a1 : j == 2 ? a2 : j == 3 ? a3 : j == 4 ? a4 : a5;
        v += y0[(size_t)n * 32 + j];               // ys node-major [n][32], k=0 slice
        float tv = tanhf(v);
        if (j < ADIM) out[n * ADIM + j] = tv;
        else          out[NN * ADIM + n * ADIM + (j - ADIM)] = expf(2.f * tv);
    }
}

// ---------------- fused dense: ys[n][k*6+a] = (relu(sum xs@W1 + b1)) @ W2[k] (+b2 k=0) ----------------
__global__ __launch_bounds__(256) void fused_dense_kernel(
        const float* __restrict__ x, const float* __restrict__ xs,
        const float* __restrict__ W1, const float* __restrict__ b1,
        const float* __restrict__ W2, const float* __restrict__ b2,
        float* __restrict__ ys) {
    __shared__ float sin_[2][32];
    __shared__ float sh[2][128];
    int t = threadIdx.x;
    int f = t & 127, half = t >> 7;
    float w1r[30];
#pragma unroll
    for (int i = 0; i < 30; ++i) w1r[i] = W1[i * FH + f];
    float b1r = b1[f];
    bool bact = t < 240;
    int bn = t / 120;
    int rem = t % 120;
    int ka = rem >> 2;          // 0..29
    int q  = rem & 3;
    int k2 = ka / 6, a2 = ka - k2 * 6;
    float w2r[32];
#pragma unroll
    for (int i = 0; i < 32; ++i)
        w2r[i] = bact ? W2[((size_t)k2 * FH + q * 32 + i) * FO + a2] : 0.f;
    float badd = (bact && k2 == 0 && q == 0) ? b2[a2] : 0.f;

    for (int n0 = blockIdx.x * 2; n0 < NN; n0 += GFUSE * 2) {
        if (t < 60) {
            int nn = t / 30, c = t - nn * 30;
            int n = n0 + nn;
            float v;
            if (c < 6) v = x[n * 6 + c];
            else       v = xs[(size_t)((c - 6) / 6) * NN8 + n * 8 + (c - 6) % 6];
            sin_[nn][c] = v;
        }
        __syncthreads();
        {
            float s = b1r;
#pragma unroll
            for (int i = 0; i < 30; ++i) s += sin_[half][i] * w1r[i];
            sh[half][f] = s > 0.f ? s : 0.f;
        }
        __syncthreads();
        if (bact) {
            float s = badd;
            const float* hr = &sh[bn][q * 32];
#pragma unroll
            for (int i = 0; i < 32; ++i) s += hr[i] * w2r[i];
            s += __shfl_xor(s, 1);
            s += __shfl_xor(s, 2);
            if (q == 0) ys[(size_t)(n0 + bn) * 32 + ka] = s;
        }
    }
}

extern "C" void kernel_launch(void* const* d_in, const int* in_sizes, int n_in,
                              void* d_out, int out_size, void* d_ws, size_t ws_size,
                              hipStream_t stream) {
    const float* x  = (const float*)d_in[0];
    const int*   ei = (const int*)d_in[1];
    const float* ew = (const float*)d_in[2];
    const float* W1 = (const float*)d_in[3];
    const float* b1 = (const float*)d_in[4];
    const float* W2 = (const float*)d_in[5];
    const float* b2 = (const float*)d_in[6];
    float* out = (float*)d_out;

    const int* row = ei;
    const int* col = ei + NE;

    // workspace layout: 16B-aligned vector arrays first
    Edge*  etmp  = (Edge*)d_ws;                 // NE            (6.4 MB)
    Edge*  edges = etmp + NE;                   // NEPAD         (6.8 MB)
    float* xpad  = (float*)(edges + NEPAD);     // NN8           (1.6 MB, 16B-aligned)
    float* xs    = xpad + NN8;                  // KH*NN8        (6.4 MB)
    float* ys    = xs + (size_t)KH * NN8;       // NN*32         (6.4 MB)
    float* za    = ys + (size_t)NN * 32;        // NN8
    float* zb    = za + NN8;                    // NN8
    u32*   ghist = (u32*)(zb + NN8);            // NBKT
    u32*   bbase = ghist + NBKT;                // NBKT+1
    u32*   bcur  = bbase + NBKT + 1;            // NBKT
    int*   offs  = (int*)(bcur + NBKT);         // NN
    int*   eoff  = offs + NN;                   // NN
    float* dinv  = (float*)(eoff + NN);         // NN

    const int B = 256;
    const int gHop = (NN * 8 + B - 1) / B;
    const int gPad = (NN8 + B - 1) / B;

    // ---- CSR build ----
    hipMemsetAsync(ghist, 0, NBKT * sizeof(u32), stream);
    bucket_hist<<<NPB, B, 0, stream>>>(col, ghist);
    bucket_scan<<<1, B, 0, stream>>>(ghist, bbase, bcur);
    partition_kernel<<<NPB, B, 0, stream>>>(row, col, ew, bcur, etmp);
    bucket_csr<<<NBKT, B, 0, stream>>>(bbase, etmp, edges, offs, eoff, dinv);
    pad_x<<<gPad, B, 0, stream>>>(x, xpad);

    // ---- layer 1: hops (hop 1 fuses normalization) ----
    hop8_norm<<<gHop, B, 0, stream>>>(offs, eoff, edges, dinv, xpad, xs);
    for (int k = 2; k <= KH; ++k)
        hop8<<<gHop, B, 0, stream>>>(offs, eoff, edges,
                                     xs + (size_t)(k - 2) * NN8, 8, 0, nullptr,
                                     xs + (size_t)(k - 1) * NN8);

    // ---- fused dense1 + relu + proj2 ----
    fused_dense_kernel<<<GFUSE, B, 0, stream>>>(x, xs, W1, b1, W2, b2, ys);

    // ---- layer 2 Horner on 6-wide ----
    hop8<<<gHop, B, 0, stream>>>(offs, eoff, edges, ys, 32, 24, ys + 18, za);
    hop8<<<gHop, B, 0, stream>>>(offs, eoff, edges, za, 8, 0, ys + 12, zb);
    hop8<<<gHop, B, 0, stream>>>(offs, eoff, edges, zb, 8, 0, ys + 6, za);
    hop8_final<<<gHop, B, 0, stream>>>(offs, eoff, edges, za, ys, out);
}

// Round 10
// 153.412 us; speedup vs baseline: 1.1009x; 1.0853x over previous
//
#include <hip/hip_runtime.h>

#define NN 50000
#define NE 800000
#define KH 4
#define FIN 6
#define FH 128
#define FO 6
#define ADIM 3
#define NN6 (NN * 6)
#define NN8 (NN * 8)
#define NBKT 196        // ceil(NN / 256) buckets of 256 node ids
#define EPB 2048        // edges per partition block
#define NPB 391         // ceil(NE / EPB)
#define CAP 6144        // LDS staging capacity per bucket (u32 edges, 24 KB)
#define ROWMASK 0xFFFFFu
#define GFUSE 2048      // grid for fused dense kernel
#define NEPAD (NE + NBKT * 1024)  // padded edge capacity (pad-to-4 per node, <=768/bucket)

typedef unsigned int u32;
typedef _Float16 f16;
typedef f16 f16x8 __attribute__((ext_vector_type(8)));

struct __align__(8) Edge { u32 r; float w; };   // staging record (20-bit row meta)

__device__ __forceinline__ float h2f_bits(u32 hb) {
    union { unsigned short us; f16 h; } c; c.us = (unsigned short)hb; return (float)c.h;
}
__device__ __forceinline__ u32 f2h_bits(float f) {
    union { unsigned short us; f16 h; } c; c.h = (f16)f; return (u32)c.us;
}
__device__ __forceinline__ u32 pack2(float a, float b) {
    return f2h_bits(a) | (f2h_bits(b) << 16);
}

// ---------------- K1: bucket histogram (col >> 8) ----------------
__global__ void bucket_hist(const int* __restrict__ col, u32* __restrict__ ghist) {
    __shared__ u32 h[NBKT];
    for (int t = threadIdx.x; t < NBKT; t += 256) h[t] = 0;
    __syncthreads();
    int base = blockIdx.x * EPB;
#pragma unroll
    for (int i = 0; i < EPB / 256; ++i) {
        int e = base + i * 256 + threadIdx.x;
        if (e < NE) atomicAdd(&h[((u32)col[e]) >> 8], 1u);
    }
    __syncthreads();
    for (int t = threadIdx.x; t < NBKT; t += 256)
        if (h[t]) atomicAdd(&ghist[t], h[t]);
}

// ---------------- K2: scan bucket counts -> bases/cursors ----------------
__global__ void bucket_scan(const u32* __restrict__ ghist, u32* __restrict__ bbase,
                            u32* __restrict__ bcur) {
    __shared__ u32 sh[256];
    int t = threadIdx.x;
    u32 v = (t < NBKT) ? ghist[t] : 0;
    sh[t] = v;
    __syncthreads();
    for (int off = 1; off < 256; off <<= 1) {
        u32 u = (t >= off) ? sh[t - off] : 0;
        __syncthreads();
        sh[t] += u;
        __syncthreads();
    }
    if (t < NBKT) { bbase[t] = sh[t] - v; bcur[t] = sh[t] - v; }
    if (t == NBKT - 1) bbase[NBKT] = sh[t];
}

// ---------------- K3: partition edges into bucket-grouped etmp (LDS-staged) ----------------
__global__ __launch_bounds__(256) void partition_kernel(
        const int* __restrict__ row, const int* __restrict__ col,
        const float* __restrict__ w, u32* __restrict__ bcur,
        Edge* __restrict__ etmp) {
    __shared__ u32 hcnt[NBKT];
    __shared__ u32 hloc[NBKT];
    __shared__ u32 hglb[NBKT];
    __shared__ u32 smeta[EPB];
    __shared__ float swt[EPB];
    __shared__ u32 sgid[EPB];
    __shared__ u32 sc[256];
    for (int t = threadIdx.x; t < NBKT; t += 256) hcnt[t] = 0;
    __syncthreads();
    int base = blockIdx.x * EPB;
    u32 m_[8]; float w_[8]; u32 b_[8]; u32 rk_[8]; int v_[8];
#pragma unroll
    for (int i = 0; i < 8; ++i) {
        int e = base + i * 256 + threadIdx.x;
        v_[i] = e < NE;
        if (v_[i]) {
            u32 c = (u32)col[e];
            u32 r = (u32)row[e];
            b_[i] = c >> 8;
            m_[i] = ((c & 255u) << 20) | r;
            w_[i] = w[e];
            rk_[i] = atomicAdd(&hcnt[b_[i]], 1u);
        }
    }
    __syncthreads();
    {   // exclusive scan of hcnt -> hloc
        int t = threadIdx.x;
        u32 v = (t < NBKT) ? hcnt[t] : 0;
        sc[t] = v;
        __syncthreads();
        for (int off = 1; off < 256; off <<= 1) {
            u32 u = (t >= off) ? sc[t - off] : 0;
            __syncthreads();
            sc[t] += u;
            __syncthreads();
        }
        if (t < NBKT) hloc[t] = sc[t] - v;
    }
    __syncthreads();
    for (int t = threadIdx.x; t < NBKT; t += 256)
        if (hcnt[t]) hglb[t] = atomicAdd(&bcur[t], hcnt[t]);
    __syncthreads();
#pragma unroll
    for (int i = 0; i < 8; ++i) if (v_[i]) {
        u32 slot = hloc[b_[i]] + rk_[i];
        smeta[slot] = m_[i];
        swt[slot] = w_[i];
        sgid[slot] = hglb[b_[i]] + rk_[i];
    }
    __syncthreads();
    int tot = NE - base; if (tot > EPB) tot = EPB;
    for (int s = threadIdx.x; s < tot; s += 256) {
        Edge ed; ed.r = smeta[s]; ed.w = swt[s];
        etmp[sgid[s]] = ed;
    }
}

// ---------------- K4: per-bucket CSR build, 4B packed edges, pad-to-4 segments ----------------
__global__ __launch_bounds__(256) void bucket_csr(
        const u32* __restrict__ bbase, const Edge* __restrict__ etmp,
        u32* __restrict__ edges, int* __restrict__ offs, int* __restrict__ eoff,
        float* __restrict__ dinv) {
    int b = blockIdx.x;
    int t = threadIdx.x;
    u32 s = bbase[b], e = bbase[b + 1];
    int cnt = (int)(e - s);
    u32 rb = s + (u32)b * 1024u;         // padded region base (each bucket +1024 slack)
    int node0 = b << 8;
    int nloc = NN - node0; if (nloc > 256) nloc = 256;
    __shared__ u32 ncnt[256];
    __shared__ float nsum[256];
    __shared__ u32 ncur[256];
    __shared__ u32 sc[256];
    __shared__ u32 stage[CAP];   // 24 KB
    ncnt[t] = 0; nsum[t] = 0.f;
    __syncthreads();
    for (int i = t; i < cnt; i += 256) {
        Edge ed = etmp[s + i];
        u32 cl = ed.r >> 20;
        atomicAdd(&ncnt[cl], 1u);
        atomicAdd(&nsum[cl], ed.w);
    }
    __syncthreads();
    u32 v = ncnt[t];
    u32 pv = (v + 3u) & ~3u;             // pad each node's segment to multiple of 4
    sc[t] = pv;
    __syncthreads();
    for (int off = 1; off < 256; off <<= 1) {
        u32 u = (t >= off) ? sc[t - off] : 0;
        __syncthreads();
        sc[t] += u;
        __syncthreads();
    }
    u32 excl = sc[t] - pv;
    u32 ptot = sc[255];
    ncur[t] = excl;
    if (t < nloc) {
        offs[node0 + t] = (int)(rb + excl);
        eoff[node0 + t] = (int)(rb + excl + pv);
        float d = nsum[t];
        dinv[node0 + t] = d > 0.f ? rsqrtf(d) : 0.f;
    }
    __syncthreads();
    for (int i = t; i < cnt; i += 256) {
        Edge ed = etmp[s + i];
        u32 cl = ed.r >> 20;
        u32 slot = atomicAdd(&ncur[cl], 1u);
        u32 pw = (ed.r & ROWMASK) | (f2h_bits(ed.w) << 16);   // row fits 16 bits (NN<65536)
        if (slot < CAP) stage[slot] = pw;
        else edges[rb + slot] = pw;
    }
    if (t < nloc) {                      // zero-edge pads
        for (u32 slot = excl + v; slot < excl + pv; ++slot) {
            if (slot < CAP) stage[slot] = 0u;
            else edges[rb + slot] = 0u;
        }
    }
    __syncthreads();
    int lim = (int)(ptot < CAP ? ptot : CAP);
    for (int i = t; i < lim; i += 256) edges[rb + i] = stage[i];
}

// ---------------- pad/convert x rows to f16 stride 8 ----------------
__global__ void pad_x(const float* __restrict__ x, f16* __restrict__ xpad) {
    int t = blockIdx.x * blockDim.x + threadIdx.x;
    if (t >= NN8) return;
    int n = t >> 3, c = t & 7;
    xpad[t] = (c < 6) ? (f16)x[n * 6 + c] : (f16)0.f;
}

// ---------------- gather: one dwordx4 = 8 f16, use 6 ----------------
__device__ __forceinline__ void gath(const f16* __restrict__ xp, u32 r, float w,
                                     float& a0, float& a1, float& a2,
                                     float& a3, float& a4, float& a5) {
    f16x8 v = *(const f16x8*)(xp + (size_t)r * 8);
    a0 += w * (float)v[0]; a1 += w * (float)v[1]; a2 += w * (float)v[2];
    a3 += w * (float)v[3]; a4 += w * (float)v[4]; a5 += w * (float)v[5];
}

#define HOP_HEAD \
    int t = blockIdx.x * blockDim.x + threadIdx.x; \
    int n = t >> 2, j = t & 3; \
    if (n >= NN) return; \
    int s = offs[n], e = eoff[n]; \
    float a0 = 0.f, a1 = 0.f, a2 = 0.f, a3 = 0.f, a4 = 0.f, a5 = 0.f;

#define HOP_REDUCE \
    _Pragma("unroll") \
    for (int d = 1; d < 4; d <<= 1) { \
        a0 += __shfl_xor(a0, d); a1 += __shfl_xor(a1, d); a2 += __shfl_xor(a2, d); \
        a3 += __shfl_xor(a3, d); a4 += __shfl_xor(a4, d); a5 += __shfl_xor(a5, d); \
    }

// ---------------- hop: 4 lanes/node, 4 edges per int4; xnext(f16,8) = yadd + A*xprev ----------------
__global__ void hop4(const int* __restrict__ offs, const int* __restrict__ eoff,
                     const u32* __restrict__ edges,
                     const f16* __restrict__ xprev, const float* __restrict__ yadd,
                     f16* __restrict__ xnext) {
    HOP_HEAD
    for (int i = s + 4 * j; i < e; i += 16) {
        int4 q = *(const int4*)(edges + i);
        { u32 wd = (u32)q.x; gath(xprev, wd & 0xFFFFu, h2f_bits(wd >> 16), a0, a1, a2, a3, a4, a5); }
        { u32 wd = (u32)q.y; gath(xprev, wd & 0xFFFFu, h2f_bits(wd >> 16), a0, a1, a2, a3, a4, a5); }
        { u32 wd = (u32)q.z; gath(xprev, wd & 0xFFFFu, h2f_bits(wd >> 16), a0, a1, a2, a3, a4, a5); }
        { u32 wd = (u32)q.w; gath(xprev, wd & 0xFFFFu, h2f_bits(wd >> 16), a0, a1, a2, a3, a4, a5); }
    }
    HOP_REDUCE
    float v0 = j == 0 ? a0 : j == 1 ? a2 : j == 2 ? a4 : 0.f;
    float v1 = j == 0 ? a1 : j == 1 ? a3 : j == 2 ? a5 : 0.f;
    if (yadd && j < 3) {
        v0 += yadd[(size_t)n * 32 + 2 * j];
        v1 += yadd[(size_t)n * 32 + 2 * j + 1];
    }
    ((u32*)xnext)[(size_t)n * 4 + j] = pack2(v0, v1);
}

// ---------------- hop variant: normalize-in-place + first hop (gathers xpad) ----------------
__global__ void hop4_norm(const int* __restrict__ offs, const int* __restrict__ eoff,
                          u32* __restrict__ edges,
                          const float* __restrict__ dinv, const f16* __restrict__ xpad,
                          f16* __restrict__ xnext) {
    HOP_HEAD
    float dn = dinv[n];
    for (int i = s + 4 * j; i < e; i += 16) {
        int4 q = *(const int4*)(edges + i);
        int4 nq;
        {
            u32 wd = (u32)q.x; u32 r = wd & 0xFFFFu;
            float wn = h2f_bits(wd >> 16) * dn * dinv[r];
            nq.x = (int)(r | (f2h_bits(wn) << 16));
            gath(xpad, r, wn, a0, a1, a2, a3, a4, a5);
        }
        {
            u32 wd = (u32)q.y; u32 r = wd & 0xFFFFu;
            float wn = h2f_bits(wd >> 16) * dn * dinv[r];
            nq.y = (int)(r | (f2h_bits(wn) << 16));
            gath(xpad, r, wn, a0, a1, a2, a3, a4, a5);
        }
        {
            u32 wd = (u32)q.z; u32 r = wd & 0xFFFFu;
            float wn = h2f_bits(wd >> 16) * dn * dinv[r];
            nq.z = (int)(r | (f2h_bits(wn) << 16));
            gath(xpad, r, wn, a0, a1, a2, a3, a4, a5);
        }
        {
            u32 wd = (u32)q.w; u32 r = wd & 0xFFFFu;
            float wn = h2f_bits(wd >> 16) * dn * dinv[r];
            nq.w = (int)(r | (f2h_bits(wn) << 16));
            gath(xpad, r, wn, a0, a1, a2, a3, a4, a5);
        }
        *(int4*)(edges + i) = nq;        // persist normalized weights
    }
    HOP_REDUCE
    float v0 = j == 0 ? a0 : j == 1 ? a2 : j == 2 ? a4 : 0.f;
    float v1 = j == 0 ? a1 : j == 1 ? a3 : j == 2 ? a5 : 0.f;
    ((u32*)xnext)[(size_t)n * 4 + j] = pack2(v0, v1);
}

// ---------------- final hop fused with tanh/exp finalize ----------------
__global__ void hop4_final(const int* __restrict__ offs, const int* __restrict__ eoff,
                           const u32* __restrict__ edges,
                           const f16* __restrict__ xprev, const float* __restrict__ y0,
                           float* __restrict__ out) {
    HOP_HEAD
    for (int i = s + 4 * j; i < e; i += 16) {
        int4 q = *(const int4*)(edges + i);
        { u32 wd = (u32)q.x; gath(xprev, wd & 0xFFFFu, h2f_bits(wd >> 16), a0, a1, a2, a3, a4, a5); }
        { u32 wd = (u32)q.y; gath(xprev, wd & 0xFFFFu, h2f_bits(wd >> 16), a0, a1, a2, a3, a4, a5); }
        { u32 wd = (u32)q.z; gath(xprev, wd & 0xFFFFu, h2f_bits(wd >> 16), a0, a1, a2, a3, a4, a5); }
        { u32 wd = (u32)q.w; gath(xprev, wd & 0xFFFFu, h2f_bits(wd >> 16), a0, a1, a2, a3, a4, a5); }
    }
    HOP_REDUCE
    if (j < 3) {
        float mv = (j == 0 ? a0 : j == 1 ? a1 : a2) + y0[(size_t)n * 32 + j];
        float sv = (j == 0 ? a3 : j == 1 ? a4 : a5) + y0[(size_t)n * 32 + 3 + j];
        out[n * ADIM + j] = tanhf(mv);
        out[NN * ADIM + n * ADIM + j] = expf(2.f * tanhf(sv));
    }
}

// ---------------- fused dense: ys/y4h = (relu(x,xs @ W1 + b1)) @ W2 ----------------
__global__ __launch_bounds__(256) void fused_dense_kernel(
        const float* __restrict__ x, const f16* __restrict__ xs,
        const float* __restrict__ W1, const float* __restrict__ b1,
        const float* __restrict__ W2, const float* __restrict__ b2,
        float* __restrict__ ys, f16* __restrict__ y4h) {
    __shared__ float sin_[2][32];
    __shared__ float sh[2][128];
    int t = threadIdx.x;
    int f = t & 127, half = t >> 7;
    float w1r[30];
#pragma unroll
    for (int i = 0; i < 30; ++i) w1r[i] = W1[i * FH + f];
    float b1r = b1[f];
    bool bact = t < 240;
    int bn = t / 120;
    int rem = t % 120;
    int ka = rem >> 2;          // 0..29
    int q  = rem & 3;
    int k2 = ka / 6, a2 = ka - k2 * 6;
    float w2r[32];
#pragma unroll
    for (int i = 0; i < 32; ++i)
        w2r[i] = bact ? W2[((size_t)k2 * FH + q * 32 + i) * FO + a2] : 0.f;
    float badd = (bact && k2 == 0 && q == 0) ? b2[a2] : 0.f;

    for (int n0 = blockIdx.x * 2; n0 < NN; n0 += GFUSE * 2) {
        if (t < 60) {
            int nn = t / 30, c = t - nn * 30;
            int n = n0 + nn;
            float v;
            if (c < 6) v = x[n * 6 + c];
            else       v = (float)xs[(size_t)((c - 6) / 6) * NN8 + n * 8 + (c - 6) % 6];
            sin_[nn][c] = v;
        }
        __syncthreads();
        {
            float s = b1r;
#pragma unroll
            for (int i = 0; i < 30; ++i) s += sin_[half][i] * w1r[i];
            sh[half][f] = s > 0.f ? s : 0.f;
        }
        __syncthreads();
        if (bact) {
            float s = badd;
            const float* hr = &sh[bn][q * 32];
#pragma unroll
            for (int i = 0; i < 32; ++i) s += hr[i] * w2r[i];
            s += __shfl_xor(s, 1);
            s += __shfl_xor(s, 2);
            if (q == 0) {
                if (ka < 24) ys[(size_t)(n0 + bn) * 32 + ka] = s;
                else         y4h[(size_t)(n0 + bn) * 8 + (ka - 24)] = (f16)s;
            }
        }
    }
}

extern "C" void kernel_launch(void* const* d_in, const int* in_sizes, int n_in,
                              void* d_out, int out_size, void* d_ws, size_t ws_size,
                              hipStream_t stream) {
    const float* x  = (const float*)d_in[0];
    const int*   ei = (const int*)d_in[1];
    const float* ew = (const float*)d_in[2];
    const float* W1 = (const float*)d_in[3];
    const float* b1 = (const float*)d_in[4];
    const float* W2 = (const float*)d_in[5];
    const float* b2 = (const float*)d_in[6];
    float* out = (float*)d_out;

    const int* row = ei;
    const int* col = ei + NE;

    // workspace layout: f16 planes first (16B-aligned, sizes multiple of 16B)
    f16*   xpad  = (f16*)d_ws;                  // NN8
    f16*   xs    = xpad + NN8;                  // KH*NN8
    f16*   y4h   = xs + (size_t)KH * NN8;       // NN8
    f16*   za    = y4h + NN8;                   // NN8
    f16*   zb    = za + NN8;                    // NN8
    float* ys    = (float*)(zb + NN8);          // NN*32 fp32
    Edge*  etmp  = (Edge*)(ys + (size_t)NN * 32);  // NE (8B)
    u32*   edges = (u32*)(etmp + NE);           // NEPAD (4B packed)
    u32*   ghist = edges + NEPAD;               // NBKT
    u32*   bbase = ghist + NBKT;                // NBKT+1
    u32*   bcur  = bbase + NBKT + 1;            // NBKT
    int*   offs  = (int*)(bcur + NBKT);         // NN
    int*   eoff  = offs + NN;                   // NN
    float* dinv  = (float*)(eoff + NN);         // NN

    const int B = 256;
    const int gHop = (NN * 4 + B - 1) / B;
    const int gPad = (NN8 + B - 1) / B;

    // ---- CSR build ----
    hipMemsetAsync(ghist, 0, NBKT * sizeof(u32), stream);
    bucket_hist<<<NPB, B, 0, stream>>>(col, ghist);
    bucket_scan<<<1, B, 0, stream>>>(ghist, bbase, bcur);
    partition_kernel<<<NPB, B, 0, stream>>>(row, col, ew, bcur, etmp);
    bucket_csr<<<NBKT, B, 0, stream>>>(bbase, etmp, edges, offs, eoff, dinv);
    pad_x<<<gPad, B, 0, stream>>>(x, xpad);

    // ---- layer 1: hops (hop 1 fuses normalization) ----
    hop4_norm<<<gHop, B, 0, stream>>>(offs, eoff, edges, dinv, xpad, xs);
    for (int k = 2; k <= KH; ++k)
        hop4<<<gHop, B, 0, stream>>>(offs, eoff, edges,
                                     xs + (size_t)(k - 2) * NN8, nullptr,
                                     xs + (size_t)(k - 1) * NN8);

    // ---- fused dense1 + relu + proj2 ----
    fused_dense_kernel<<<GFUSE, B, 0, stream>>>(x, xs, W1, b1, W2, b2, ys, y4h);

    // ---- layer 2 Horner on 6-wide ----
    hop4<<<gHop, B, 0, stream>>>(offs, eoff, edges, y4h, ys + 18, za);
    hop4<<<gHop, B, 0, stream>>>(offs, eoff, edges, za, ys + 12, zb);
    hop4<<<gHop, B, 0, stream>>>(offs, eoff, edges, zb, ys + 6, za);
    hop4_final<<<gHop, B, 0, stream>>>(offs, eoff, edges, za, ys, out);
}